// Round 1
// baseline (1045.217 us; speedup 1.0000x reference)
//
#include <hip/hip_runtime.h>

typedef unsigned short u16;
typedef unsigned int u32;
typedef __attribute__((ext_vector_type(8))) short bf16x8;
typedef __attribute__((ext_vector_type(4))) float f32x4;

#define BM 128
#define BN 64
#define BK 64
#define LDK 72   // pad 64 -> 72 to break 128B-stride LDS bank conflicts

__device__ __forceinline__ u16 f2bf(float f) {
    u32 u = __float_as_uint(f);
    u += 0x7fffu + ((u >> 16) & 1u);   // round-to-nearest-even
    return (u16)(u >> 16);
}

// ---------------- prep kernels ----------------

// blocks 0..31: U[f][j] = sum_k w_num[f][k] * W_first[f*256+k][j]
//               P[f][j] = sum_k b_num[f][k] * W_first[f*256+k][j]
__global__ __launch_bounds__(256) void prep_u_kernel(
    const float* __restrict__ w_num, const float* __restrict__ b_num,
    const float* __restrict__ W_first, float* __restrict__ U, float* __restrict__ P)
{
    __shared__ float wrow[256];
    __shared__ float brow[256];
    int j = threadIdx.x, f = blockIdx.x;
    wrow[j] = w_num[f * 256 + j];
    brow[j] = b_num[f * 256 + j];
    __syncthreads();
    float au = 0.f, ap = 0.f;
    for (int k = 0; k < 256; k++) {
        float w = W_first[(size_t)((f << 8) + k) * 256 + j];
        au = fmaf(wrow[k], w, au);
        ap = fmaf(brow[k], w, ap);
    }
    U[f * 256 + j] = au;
    P[f * 256 + j] = ap;
}

// c0[j] = b_first[j] + sum_f P[f][j]
__global__ __launch_bounds__(256) void prep_c0_kernel(
    const float* __restrict__ b_first, const float* __restrict__ P, float* __restrict__ c0)
{
    int j = threadIdx.x;
    float a = b_first[j];
    for (int f = 0; f < 32; f++) a += P[f * 256 + j];
    c0[j] = a;
}

// WcT[j][k] (256 x 4160 bf16): k<4096 -> W_first[8192+k][j]; k<4128 -> U[k-4096][j]; else 0
__global__ __launch_bounds__(256) void prep_wcat_kernel(
    const float* __restrict__ W_first, const float* __restrict__ U, u16* __restrict__ WcT)
{
    int k = blockIdx.x;   // 0..4159
    int j = threadIdx.x;  // 0..255
    float v;
    if (k < 4096)      v = W_first[(size_t)(8192 + k) * 256 + j];
    else if (k < 4128) v = U[(k - 4096) * 256 + j];
    else               v = 0.f;
    WcT[(size_t)j * 4160 + k] = f2bf(v);
}

// W1s [8][256][512] -> W1T [8][512][256]  (BT layout: [n][k])
__global__ __launch_bounds__(256) void prep_w1t_kernel(
    const float* __restrict__ W1s, u16* __restrict__ W1T)
{
    int bk = blockIdx.x;             // l*256 + k
    int l = bk >> 8, k = bk & 255;
    int n = threadIdx.x;
    for (int h = 0; h < 2; h++) {
        int nn = n + h * 256;
        float v = W1s[(size_t)l * 131072 + (size_t)k * 512 + nn];
        W1T[(size_t)l * 131072 + (size_t)nn * 256 + k] = f2bf(v);
    }
}

// W2s [8][512][256] -> W2T [8][256][512]
__global__ __launch_bounds__(256) void prep_w2t_kernel(
    const float* __restrict__ W2s, u16* __restrict__ W2T)
{
    int bk = blockIdx.x;             // l*512 + k
    int l = bk >> 9, k = bk & 511;
    int n = threadIdx.x;
    float v = W2s[(size_t)l * 131072 + (size_t)k * 256 + n];
    W2T[(size_t)l * 131072 + (size_t)n * 512 + k] = f2bf(v);
}

// ---------------- GEMM ----------------
// C[M x N] = A[M x K] @ BT[N x K]^T, 128x64 tile, BK=64, 4 waves (each 32 rows x 64 cols).
// MODE 0: A gathered fp32 (cat_embed / x_num / zero-pad), +bias, fp32 out
// MODE 1: A bf16, +bias, ReLU, bf16 out
// MODE 2: A bf16, +bias +resid, fp32 out (in-place on resid allowed)
template <int MODE>
__global__ __launch_bounds__(256) void gemm_kernel(
    const u16* __restrict__ A, const u16* __restrict__ BT,
    const float* __restrict__ bias, const float* __restrict__ resid,
    float* __restrict__ outF, u16* __restrict__ outH,
    int K, int N,
    const int* __restrict__ cidx, const float* __restrict__ cemb,
    const float* __restrict__ xnum)
{
    __shared__ __align__(16) u16 Ab[BM * LDK];
    __shared__ __align__(16) u16 Bb[BN * LDK];
    const int tid = threadIdx.x;
    const int lane = tid & 63;
    const int wv = tid >> 6;
    const int quad = lane >> 4;
    const int l16 = lane & 15;
    const int m0 = blockIdx.y * BM;
    const int n0 = blockIdx.x * BN;

    f32x4 acc[2][4];
#pragma unroll
    for (int i = 0; i < 2; i++)
#pragma unroll
        for (int j = 0; j < 4; j++) acc[i][j] = (f32x4){0.f, 0.f, 0.f, 0.f};

    for (int k0 = 0; k0 < K; k0 += BK) {
        // ---- stage A ----
        if (MODE == 0) {
#pragma unroll
            for (int it = 0; it < 8; it++) {
                int chunk = tid + it * 256;   // 2048 float4 chunks
                int r = chunk >> 4;           // row 0..127
                int c4 = chunk & 15;
                int k = k0 + c4 * 4;
                int b = m0 + r;
                float4 v;
                if (k < 4096) {
                    int f = k >> 8;
                    int rowi = cidx[b * 16 + f];
                    v = *(const float4*)&cemb[rowi * 256 + (k & 255)];
                } else if (k < 4128) {
                    v = *(const float4*)&xnum[b * 32 + (k - 4096)];
                } else {
                    v = make_float4(0.f, 0.f, 0.f, 0.f);
                }
                u16* dst = &Ab[r * LDK + c4 * 4];
                dst[0] = f2bf(v.x); dst[1] = f2bf(v.y);
                dst[2] = f2bf(v.z); dst[3] = f2bf(v.w);
            }
        } else {
#pragma unroll
            for (int it = 0; it < 4; it++) {
                int chunk = tid + it * 256;   // 1024 chunks of 8 bf16
                int r = chunk >> 3;
                int c8 = chunk & 7;
                *(bf16x8*)&Ab[r * LDK + c8 * 8] =
                    *(const bf16x8*)&A[(size_t)(m0 + r) * K + k0 + c8 * 8];
            }
        }
        // ---- stage BT ----
#pragma unroll
        for (int it = 0; it < 2; it++) {
            int chunk = tid + it * 256;       // 512 chunks
            int r = chunk >> 3;               // n row 0..63
            int c8 = chunk & 7;
            *(bf16x8*)&Bb[r * LDK + c8 * 8] =
                *(const bf16x8*)&BT[(size_t)(n0 + r) * K + k0 + c8 * 8];
        }
        __syncthreads();

#pragma unroll
        for (int kk = 0; kk < BK; kk += 32) {
            bf16x8 af[2], bfr[4];
#pragma unroll
            for (int i = 0; i < 2; i++)
                af[i] = *(const bf16x8*)&Ab[(wv * 32 + i * 16 + l16) * LDK + kk + quad * 8];
#pragma unroll
            for (int j = 0; j < 4; j++)
                bfr[j] = *(const bf16x8*)&Bb[(j * 16 + l16) * LDK + kk + quad * 8];
#pragma unroll
            for (int i = 0; i < 2; i++)
#pragma unroll
                for (int j = 0; j < 4; j++)
                    acc[i][j] = __builtin_amdgcn_mfma_f32_16x16x32_bf16(
                        af[i], bfr[j], acc[i][j], 0, 0, 0);
        }
        __syncthreads();
    }

    // ---- epilogue ----
    // C/D layout (16x16x32): col = lane&15, row = (lane>>4)*4 + reg
#pragma unroll
    for (int i = 0; i < 2; i++) {
#pragma unroll
        for (int j = 0; j < 4; j++) {
            int col = n0 + j * 16 + l16;
            float bs = bias[col];
#pragma unroll
            for (int r = 0; r < 4; r++) {
                int row = m0 + wv * 32 + i * 16 + quad * 4 + r;
                float v = acc[i][j][r] + bs;
                if (MODE == 0) {
                    outF[(size_t)row * N + col] = v;
                } else if (MODE == 1) {
                    v = v > 0.f ? v : 0.f;
                    outH[(size_t)row * N + col] = f2bf(v);
                } else {
                    outF[(size_t)row * N + col] = v + resid[(size_t)row * N + col];
                }
            }
        }
    }
}

// ---------------- LayerNorm: h (fp32) -> hn (bf16) ----------------
__global__ __launch_bounds__(256) void ln_kernel(
    const float* __restrict__ h, const float* __restrict__ g,
    const float* __restrict__ bta, u16* __restrict__ out)
{
    int lane = threadIdx.x & 63;
    int row = blockIdx.x * 4 + (threadIdx.x >> 6);
    const float4 x = *(const float4*)&h[(size_t)row * 256 + lane * 4];
    float s = x.x + x.y + x.z + x.w;
    float s2 = x.x * x.x + x.y * x.y + x.z * x.z + x.w * x.w;
    for (int o = 32; o > 0; o >>= 1) { s += __shfl_xor(s, o); s2 += __shfl_xor(s2, o); }
    float mu = s * (1.f / 256.f);
    float var = s2 * (1.f / 256.f) - mu * mu;
    float rs = rsqrtf(var + 1e-5f);
    float4 gv = *(const float4*)&g[lane * 4];
    float4 bv = *(const float4*)&bta[lane * 4];
    ushort4 o4;
    o4.x = f2bf((x.x - mu) * rs * gv.x + bv.x);
    o4.y = f2bf((x.y - mu) * rs * gv.y + bv.y);
    o4.z = f2bf((x.z - mu) * rs * gv.z + bv.z);
    o4.w = f2bf((x.w - mu) * rs * gv.w + bv.w);
    *(ushort4*)&out[(size_t)row * 256 + lane * 4] = o4;
}

// ---------------- head: final LN + [256 x 2] matvec ----------------
__global__ __launch_bounds__(256) void head_kernel(
    const float* __restrict__ h, const float* __restrict__ g,
    const float* __restrict__ bta, const float* __restrict__ Wh,
    const float* __restrict__ bh, float* __restrict__ out)
{
    int lane = threadIdx.x & 63;
    int row = blockIdx.x * 4 + (threadIdx.x >> 6);
    const float4 x = *(const float4*)&h[(size_t)row * 256 + lane * 4];
    float s = x.x + x.y + x.z + x.w;
    float s2 = x.x * x.x + x.y * x.y + x.z * x.z + x.w * x.w;
    for (int o = 32; o > 0; o >>= 1) { s += __shfl_xor(s, o); s2 += __shfl_xor(s2, o); }
    float mu = s * (1.f / 256.f);
    float rs = rsqrtf(s2 * (1.f / 256.f) - mu * mu + 1e-5f);
    float4 gv = *(const float4*)&g[lane * 4];
    float4 bv = *(const float4*)&bta[lane * 4];
    float xn0 = (x.x - mu) * rs * gv.x + bv.x;
    float xn1 = (x.y - mu) * rs * gv.y + bv.y;
    float xn2 = (x.z - mu) * rs * gv.z + bv.z;
    float xn3 = (x.w - mu) * rs * gv.w + bv.w;
    // Wh row-major [256][2]; lane covers rows lane*4 .. lane*4+3
    float4 wa = *(const float4*)&Wh[lane * 8];
    float4 wb = *(const float4*)&Wh[lane * 8 + 4];
    float d0 = xn0 * wa.x + xn1 * wa.z + xn2 * wb.x + xn3 * wb.z;
    float d1 = xn0 * wa.y + xn1 * wa.w + xn2 * wb.y + xn3 * wb.w;
    for (int o = 32; o > 0; o >>= 1) { d0 += __shfl_xor(d0, o); d1 += __shfl_xor(d1, o); }
    if (lane == 0) {
        out[(size_t)row * 2 + 0] = d0 + bh[0];
        out[(size_t)row * 2 + 1] = d1 + bh[1];
    }
}

// ---------------- launch ----------------
extern "C" void kernel_launch(void* const* d_in, const int* in_sizes, int n_in,
                              void* d_out, int out_size, void* d_ws, size_t ws_size,
                              hipStream_t stream)
{
    const float* x_num   = (const float*)d_in[0];
    const int*   cidx    = (const int*)d_in[1];
    const float* w_num   = (const float*)d_in[2];
    const float* b_num   = (const float*)d_in[3];
    const float* cemb    = (const float*)d_in[4];
    const float* W_first = (const float*)d_in[5];
    const float* b_first = (const float*)d_in[6];
    const float* ln_g    = (const float*)d_in[7];
    const float* ln_b    = (const float*)d_in[8];
    const float* W1s     = (const float*)d_in[9];
    const float* b1s     = (const float*)d_in[10];
    const float* W2s     = (const float*)d_in[11];
    const float* b2s     = (const float*)d_in[12];
    const float* g_f     = (const float*)d_in[13];
    const float* beta_f  = (const float*)d_in[14];
    const float* W_head  = (const float*)d_in[15];
    const float* b_head  = (const float*)d_in[16];
    float* out = (float*)d_out;

    char* ws = (char*)d_ws;
    float* U   = (float*)(ws + 0);          //  32 KB
    float* c0  = (float*)(ws + 32768);      //   1 KB
    float* P   = (float*)(ws + 33792);      //  32 KB
    u16* WcT   = (u16*)(ws + 66560);        // 256 x 4160 bf16
    u16* W1T   = (u16*)(ws + 2196480);      // 8 x 512 x 256 bf16
    u16* W2T   = (u16*)(ws + 4293632);      // 8 x 256 x 512 bf16
    float* h   = (float*)(ws + 6390784);    // 16384 x 256 f32
    u16* hn    = (u16*)(ws + 23168000);     // 16384 x 256 bf16
    u16* hid   = (u16*)(ws + 31556608);     // 16384 x 512 bf16
    // total ~48.3 MB

    prep_u_kernel<<<32, 256, 0, stream>>>(w_num, b_num, W_first, U, P);
    prep_c0_kernel<<<1, 256, 0, stream>>>(b_first, P, c0);
    prep_wcat_kernel<<<4160, 256, 0, stream>>>(W_first, U, WcT);
    prep_w1t_kernel<<<2048, 256, 0, stream>>>(W1s, W1T);
    prep_w2t_kernel<<<4096, 256, 0, stream>>>(W2s, W2T);

    // first layer: h = [cat gathers | x_num | pad] @ WcT^T + c0
    gemm_kernel<0><<<dim3(256 / BN, 16384 / BM), 256, 0, stream>>>(
        nullptr, WcT, c0, nullptr, h, nullptr, 4160, 256, cidx, cemb, x_num);

    for (int l = 0; l < 8; l++) {
        ln_kernel<<<4096, 256, 0, stream>>>(h, ln_g + l * 256, ln_b + l * 256, hn);
        gemm_kernel<1><<<dim3(512 / BN, 16384 / BM), 256, 0, stream>>>(
            hn, W1T + (size_t)l * 131072, b1s + l * 512, nullptr, nullptr, hid,
            256, 512, nullptr, nullptr, nullptr);
        gemm_kernel<2><<<dim3(256 / BN, 16384 / BM), 256, 0, stream>>>(
            hid, W2T + (size_t)l * 131072, b2s + l * 256, h, h, nullptr,
            512, 256, nullptr, nullptr, nullptr);
    }
    head_kernel<<<4096, 256, 0, stream>>>(h, g_f, beta_f, W_head, b_head, out);
}

// Round 2
// 726.984 us; speedup vs baseline: 1.4377x; 1.4377x over previous
//
#include <hip/hip_runtime.h>

typedef unsigned short u16;
typedef unsigned int u32;
typedef __attribute__((ext_vector_type(8))) short bf16x8;
typedef __attribute__((ext_vector_type(4))) float f32x4;

#define BM 128
#define BN 64
#define BK 64
#define LDK 72   // pad 64 -> 72 to break 128B-stride LDS bank conflicts

__device__ __forceinline__ u16 f2bf(float f) {
    u32 u = __float_as_uint(f);
    u += 0x7fffu + ((u >> 16) & 1u);   // round-to-nearest-even
    return (u16)(u >> 16);
}

// ---------------- prep kernels ----------------

__global__ __launch_bounds__(256) void prep_u_kernel(
    const float* __restrict__ w_num, const float* __restrict__ b_num,
    const float* __restrict__ W_first, float* __restrict__ U, float* __restrict__ P)
{
    __shared__ float wrow[256];
    __shared__ float brow[256];
    int j = threadIdx.x, f = blockIdx.x;
    wrow[j] = w_num[f * 256 + j];
    brow[j] = b_num[f * 256 + j];
    __syncthreads();
    float au = 0.f, ap = 0.f;
    for (int k = 0; k < 256; k++) {
        float w = W_first[(size_t)((f << 8) + k) * 256 + j];
        au = fmaf(wrow[k], w, au);
        ap = fmaf(brow[k], w, ap);
    }
    U[f * 256 + j] = au;
    P[f * 256 + j] = ap;
}

__global__ __launch_bounds__(256) void prep_c0_kernel(
    const float* __restrict__ b_first, const float* __restrict__ P, float* __restrict__ c0)
{
    int j = threadIdx.x;
    float a = b_first[j];
    for (int f = 0; f < 32; f++) a += P[f * 256 + j];
    c0[j] = a;
}

// WcT[j][k] (256 x 4160 bf16): k<4096 -> W_first[8192+k][j]; k<4128 -> U[k-4096][j]; else 0
__global__ __launch_bounds__(256) void prep_wcat_kernel(
    const float* __restrict__ W_first, const float* __restrict__ U, u16* __restrict__ WcT)
{
    int k = blockIdx.x;   // 0..4159
    int j = threadIdx.x;  // 0..255
    float v;
    if (k < 4096)      v = W_first[(size_t)(8192 + k) * 256 + j];
    else if (k < 4128) v = U[(k - 4096) * 256 + j];
    else               v = 0.f;
    WcT[(size_t)j * 4160 + k] = f2bf(v);
}

__global__ __launch_bounds__(256) void prep_w1t_kernel(
    const float* __restrict__ W1s, u16* __restrict__ W1T)
{
    int bk = blockIdx.x;             // l*256 + k
    int l = bk >> 8, k = bk & 255;
    int n = threadIdx.x;
    for (int h = 0; h < 2; h++) {
        int nn = n + h * 256;
        float v = W1s[(size_t)l * 131072 + (size_t)k * 512 + nn];
        W1T[(size_t)l * 131072 + (size_t)nn * 256 + k] = f2bf(v);
    }
}

__global__ __launch_bounds__(256) void prep_w2t_kernel(
    const float* __restrict__ W2s, u16* __restrict__ W2T)
{
    int bk = blockIdx.x;             // l*512 + k
    int l = bk >> 9, k = bk & 511;
    int n = threadIdx.x;
    float v = W2s[(size_t)l * 131072 + (size_t)k * 256 + n];
    W2T[(size_t)l * 131072 + (size_t)n * 512 + k] = f2bf(v);
}

// ---------------- first layer: gathered-A GEMM, BM=32 x full N=256 ----------------
// h[32-row tile][256] = [cat gathers | x_num | pad](K=4160) @ WcT^T + c0
// One block covers ALL of N -> each row's embeddings gathered exactly once.
#define FBM 32
__global__ __launch_bounds__(256) void first_gemm_kernel(
    const u16* __restrict__ BT, const float* __restrict__ bias,
    float* __restrict__ outF,
    const int* __restrict__ cidx, const float* __restrict__ cemb,
    const float* __restrict__ xnum)
{
    __shared__ __align__(16) u16 Ab[FBM * LDK];
    __shared__ __align__(16) u16 Bb[256 * LDK];
    __shared__ int   sidx[FBM * 16];
    __shared__ float sx[FBM * 32];

    const int tid = threadIdx.x;
    const int lane = tid & 63;
    const int wv = tid >> 6;
    const int quad = lane >> 4;
    const int l16 = lane & 15;
    const int m0 = blockIdx.x * FBM;

    // stage this tile's categorical indices (512 ints) and numeric values (1024 f32)
#pragma unroll
    for (int i = 0; i < 2; i++) sidx[tid + i * 256] = cidx[m0 * 16 + tid + i * 256];
    {
        float4 v = *(const float4*)&xnum[(size_t)m0 * 32 + tid * 4];
        sx[tid * 4 + 0] = v.x; sx[tid * 4 + 1] = v.y;
        sx[tid * 4 + 2] = v.z; sx[tid * 4 + 3] = v.w;
    }
    __syncthreads();

    f32x4 acc[2][4];
#pragma unroll
    for (int i = 0; i < 2; i++)
#pragma unroll
        for (int j = 0; j < 4; j++) acc[i][j] = (f32x4){0.f, 0.f, 0.f, 0.f};

    for (int k0 = 0; k0 < 4160; k0 += BK) {
        // ---- stage A: 32 rows x 64 cols, gathered fp32 -> bf16 ----
#pragma unroll
        for (int it = 0; it < 2; it++) {
            int chunk = tid + it * 256;   // 512 float4 chunks
            int r = chunk >> 4;           // row 0..31
            int c4 = chunk & 15;
            int k = k0 + c4 * 4;
            float4 v;
            if (k < 4096) {
                int f = k >> 8;
                int rowi = sidx[r * 16 + f];
                v = *(const float4*)&cemb[(size_t)rowi * 256 + (k & 255)];
            } else if (k < 4128) {
                int c = k - 4096;
                v.x = sx[r * 32 + c];     v.y = sx[r * 32 + c + 1];
                v.z = sx[r * 32 + c + 2]; v.w = sx[r * 32 + c + 3];
            } else {
                v = make_float4(0.f, 0.f, 0.f, 0.f);
            }
            u16* dst = &Ab[r * LDK + c4 * 4];
            dst[0] = f2bf(v.x); dst[1] = f2bf(v.y);
            dst[2] = f2bf(v.z); dst[3] = f2bf(v.w);
        }
        // ---- stage B: all 256 N-rows x 64 cols ----
#pragma unroll
        for (int it = 0; it < 8; it++) {
            int chunk = tid + it * 256;   // 2048 chunks of 8 bf16
            int r = chunk >> 3;           // n row 0..255
            int c8 = chunk & 7;
            *(bf16x8*)&Bb[r * LDK + c8 * 8] =
                *(const bf16x8*)&BT[(size_t)r * 4160 + k0 + c8 * 8];
        }
        __syncthreads();

#pragma unroll
        for (int kk = 0; kk < BK; kk += 32) {
            bf16x8 af[2], bfr[4];
#pragma unroll
            for (int i = 0; i < 2; i++)
                af[i] = *(const bf16x8*)&Ab[(i * 16 + l16) * LDK + kk + quad * 8];
#pragma unroll
            for (int j = 0; j < 4; j++)
                bfr[j] = *(const bf16x8*)&Bb[(wv * 64 + j * 16 + l16) * LDK + kk + quad * 8];
#pragma unroll
            for (int i = 0; i < 2; i++)
#pragma unroll
                for (int j = 0; j < 4; j++)
                    acc[i][j] = __builtin_amdgcn_mfma_f32_16x16x32_bf16(
                        af[i], bfr[j], acc[i][j], 0, 0, 0);
        }
        __syncthreads();
    }

    // C/D layout (16x16x32): col = lane&15, row = (lane>>4)*4 + reg
#pragma unroll
    for (int i = 0; i < 2; i++) {
#pragma unroll
        for (int j = 0; j < 4; j++) {
            int col = wv * 64 + j * 16 + l16;
            float bs = bias[col];
#pragma unroll
            for (int r = 0; r < 4; r++) {
                int row = m0 + i * 16 + quad * 4 + r;
                outF[(size_t)row * 256 + col] = acc[i][j][r] + bs;
            }
        }
    }
}

// ---------------- FC GEMM ----------------
// C[M x N] = A[M x K] @ BT[N x K]^T, 128x64 tile, BK=64, 4 waves.
// MODE 1: A bf16, +bias, ReLU, bf16 out
// MODE 2: A bf16, +bias +resid, fp32 out (in-place on resid allowed)
template <int MODE>
__global__ __launch_bounds__(256) void gemm_kernel(
    const u16* __restrict__ A, const u16* __restrict__ BT,
    const float* __restrict__ bias, const float* __restrict__ resid,
    float* __restrict__ outF, u16* __restrict__ outH,
    int K, int N)
{
    __shared__ __align__(16) u16 Ab[BM * LDK];
    __shared__ __align__(16) u16 Bb[BN * LDK];
    const int tid = threadIdx.x;
    const int lane = tid & 63;
    const int wv = tid >> 6;
    const int quad = lane >> 4;
    const int l16 = lane & 15;
    const int m0 = blockIdx.y * BM;
    const int n0 = blockIdx.x * BN;

    f32x4 acc[2][4];
#pragma unroll
    for (int i = 0; i < 2; i++)
#pragma unroll
        for (int j = 0; j < 4; j++) acc[i][j] = (f32x4){0.f, 0.f, 0.f, 0.f};

    for (int k0 = 0; k0 < K; k0 += BK) {
#pragma unroll
        for (int it = 0; it < 4; it++) {
            int chunk = tid + it * 256;   // 1024 chunks of 8 bf16
            int r = chunk >> 3;
            int c8 = chunk & 7;
            *(bf16x8*)&Ab[r * LDK + c8 * 8] =
                *(const bf16x8*)&A[(size_t)(m0 + r) * K + k0 + c8 * 8];
        }
#pragma unroll
        for (int it = 0; it < 2; it++) {
            int chunk = tid + it * 256;       // 512 chunks
            int r = chunk >> 3;               // n row 0..63
            int c8 = chunk & 7;
            *(bf16x8*)&Bb[r * LDK + c8 * 8] =
                *(const bf16x8*)&BT[(size_t)(n0 + r) * K + k0 + c8 * 8];
        }
        __syncthreads();

#pragma unroll
        for (int kk = 0; kk < BK; kk += 32) {
            bf16x8 af[2], bfr[4];
#pragma unroll
            for (int i = 0; i < 2; i++)
                af[i] = *(const bf16x8*)&Ab[(wv * 32 + i * 16 + l16) * LDK + kk + quad * 8];
#pragma unroll
            for (int j = 0; j < 4; j++)
                bfr[j] = *(const bf16x8*)&Bb[(j * 16 + l16) * LDK + kk + quad * 8];
#pragma unroll
            for (int i = 0; i < 2; i++)
#pragma unroll
                for (int j = 0; j < 4; j++)
                    acc[i][j] = __builtin_amdgcn_mfma_f32_16x16x32_bf16(
                        af[i], bfr[j], acc[i][j], 0, 0, 0);
        }
        __syncthreads();
    }

#pragma unroll
    for (int i = 0; i < 2; i++) {
#pragma unroll
        for (int j = 0; j < 4; j++) {
            int col = n0 + j * 16 + l16;
            float bs = bias[col];
#pragma unroll
            for (int r = 0; r < 4; r++) {
                int row = m0 + wv * 32 + i * 16 + quad * 4 + r;
                float v = acc[i][j][r] + bs;
                if (MODE == 1) {
                    v = v > 0.f ? v : 0.f;
                    outH[(size_t)row * N + col] = f2bf(v);
                } else {
                    outF[(size_t)row * N + col] = v + resid[(size_t)row * N + col];
                }
            }
        }
    }
}

// ---------------- LayerNorm: h (fp32) -> hn (bf16) ----------------
__global__ __launch_bounds__(256) void ln_kernel(
    const float* __restrict__ h, const float* __restrict__ g,
    const float* __restrict__ bta, u16* __restrict__ out)
{
    int lane = threadIdx.x & 63;
    int row = blockIdx.x * 4 + (threadIdx.x >> 6);
    const float4 x = *(const float4*)&h[(size_t)row * 256 + lane * 4];
    float s = x.x + x.y + x.z + x.w;
    float s2 = x.x * x.x + x.y * x.y + x.z * x.z + x.w * x.w;
    for (int o = 32; o > 0; o >>= 1) { s += __shfl_xor(s, o); s2 += __shfl_xor(s2, o); }
    float mu = s * (1.f / 256.f);
    float var = s2 * (1.f / 256.f) - mu * mu;
    float rs = rsqrtf(var + 1e-5f);
    float4 gv = *(const float4*)&g[lane * 4];
    float4 bv = *(const float4*)&bta[lane * 4];
    ushort4 o4;
    o4.x = f2bf((x.x - mu) * rs * gv.x + bv.x);
    o4.y = f2bf((x.y - mu) * rs * gv.y + bv.y);
    o4.z = f2bf((x.z - mu) * rs * gv.z + bv.z);
    o4.w = f2bf((x.w - mu) * rs * gv.w + bv.w);
    *(ushort4*)&out[(size_t)row * 256 + lane * 4] = o4;
}

// ---------------- head: final LN + [256 x 2] matvec ----------------
__global__ __launch_bounds__(256) void head_kernel(
    const float* __restrict__ h, const float* __restrict__ g,
    const float* __restrict__ bta, const float* __restrict__ Wh,
    const float* __restrict__ bh, float* __restrict__ out)
{
    int lane = threadIdx.x & 63;
    int row = blockIdx.x * 4 + (threadIdx.x >> 6);
    const float4 x = *(const float4*)&h[(size_t)row * 256 + lane * 4];
    float s = x.x + x.y + x.z + x.w;
    float s2 = x.x * x.x + x.y * x.y + x.z * x.z + x.w * x.w;
    for (int o = 32; o > 0; o >>= 1) { s += __shfl_xor(s, o); s2 += __shfl_xor(s2, o); }
    float mu = s * (1.f / 256.f);
    float rs = rsqrtf(s2 * (1.f / 256.f) - mu * mu + 1e-5f);
    float4 gv = *(const float4*)&g[lane * 4];
    float4 bv = *(const float4*)&bta[lane * 4];
    float xn0 = (x.x - mu) * rs * gv.x + bv.x;
    float xn1 = (x.y - mu) * rs * gv.y + bv.y;
    float xn2 = (x.z - mu) * rs * gv.z + bv.z;
    float xn3 = (x.w - mu) * rs * gv.w + bv.w;
    float4 wa = *(const float4*)&Wh[lane * 8];
    float4 wb = *(const float4*)&Wh[lane * 8 + 4];
    float d0 = xn0 * wa.x + xn1 * wa.z + xn2 * wb.x + xn3 * wb.z;
    float d1 = xn0 * wa.y + xn1 * wa.w + xn2 * wb.y + xn3 * wb.w;
    for (int o = 32; o > 0; o >>= 1) { d0 += __shfl_xor(d0, o); d1 += __shfl_xor(d1, o); }
    if (lane == 0) {
        out[(size_t)row * 2 + 0] = d0 + bh[0];
        out[(size_t)row * 2 + 1] = d1 + bh[1];
    }
}

// ---------------- launch ----------------
extern "C" void kernel_launch(void* const* d_in, const int* in_sizes, int n_in,
                              void* d_out, int out_size, void* d_ws, size_t ws_size,
                              hipStream_t stream)
{
    const float* x_num   = (const float*)d_in[0];
    const int*   cidx    = (const int*)d_in[1];
    const float* w_num   = (const float*)d_in[2];
    const float* b_num   = (const float*)d_in[3];
    const float* cemb    = (const float*)d_in[4];
    const float* W_first = (const float*)d_in[5];
    const float* b_first = (const float*)d_in[6];
    const float* ln_g    = (const float*)d_in[7];
    const float* ln_b    = (const float*)d_in[8];
    const float* W1s     = (const float*)d_in[9];
    const float* b1s     = (const float*)d_in[10];
    const float* W2s     = (const float*)d_in[11];
    const float* b2s     = (const float*)d_in[12];
    const float* g_f     = (const float*)d_in[13];
    const float* beta_f  = (const float*)d_in[14];
    const float* W_head  = (const float*)d_in[15];
    const float* b_head  = (const float*)d_in[16];
    float* out = (float*)d_out;

    char* ws = (char*)d_ws;
    float* U   = (float*)(ws + 0);          //  32 KB
    float* c0  = (float*)(ws + 32768);      //   1 KB
    float* P   = (float*)(ws + 33792);      //  32 KB
    u16* WcT   = (u16*)(ws + 66560);        // 256 x 4160 bf16
    u16* W1T   = (u16*)(ws + 2196480);      // 8 x 512 x 256 bf16
    u16* W2T   = (u16*)(ws + 4293632);      // 8 x 256 x 512 bf16
    float* h   = (float*)(ws + 6390784);    // 16384 x 256 f32
    u16* hn    = (u16*)(ws + 23168000);     // 16384 x 256 bf16
    u16* hid   = (u16*)(ws + 31556608);     // 16384 x 512 bf16

    prep_u_kernel<<<32, 256, 0, stream>>>(w_num, b_num, W_first, U, P);
    prep_c0_kernel<<<1, 256, 0, stream>>>(b_first, P, c0);
    prep_wcat_kernel<<<4160, 256, 0, stream>>>(W_first, U, WcT);
    prep_w1t_kernel<<<2048, 256, 0, stream>>>(W1s, W1T);
    prep_w2t_kernel<<<4096, 256, 0, stream>>>(W2s, W2T);

    // first layer: gathered-A GEMM, one block per 32 rows covering all N
    first_gemm_kernel<<<16384 / FBM, 256, 0, stream>>>(
        WcT, c0, h, cidx, cemb, x_num);

    for (int l = 0; l < 8; l++) {
        ln_kernel<<<4096, 256, 0, stream>>>(h, ln_g + l * 256, ln_b + l * 256, hn);
        gemm_kernel<1><<<dim3(512 / BN, 16384 / BM), 256, 0, stream>>>(
            hn, W1T + (size_t)l * 131072, b1s + l * 512, nullptr, nullptr, hid,
            256, 512);
        gemm_kernel<2><<<dim3(256 / BN, 16384 / BM), 256, 0, stream>>>(
            hid, W2T + (size_t)l * 131072, b2s + l * 256, h, h, nullptr,
            512, 256);
    }
    head_kernel<<<4096, 256, 0, stream>>>(h, g_f, beta_f, W_head, b_head, out);
}